// Round 14
// baseline (3384.875 us; speedup 1.0000x reference)
//
#include <hip/hip_runtime.h>
#include <math.h>

#define B_   256
#define H_   512
#define V_   16000
#define M_   32
#define SOS_ 1
#define EOS_ 2
#define INV_SCALE (1.0f/2048.0f)

typedef _Float16 half_t;
typedef _Float16 f16x8 __attribute__((ext_vector_type(8)));
typedef _Float16 f16x4 __attribute__((ext_vector_type(4)));
typedef float    f32x4 __attribute__((ext_vector_type(4)));

__device__ __forceinline__ void split_f32(float x, half_t& a, half_t& b) {
    a = (half_t)x;
    b = (half_t)((x - (float)a) * 2048.0f);
}

// ---------------------------------------------------------------------------
// one-time weight split: fp32 -> fp16 hi/lo planes
// ---------------------------------------------------------------------------
__global__ __launch_bounds__(256)
void split_weights_k(const float* __restrict__ src, half_t* __restrict__ hi,
                     half_t* __restrict__ lo, int n4)
{
    const int i = blockIdx.x * 256 + threadIdx.x;
    if (i >= n4) return;
    const float4 v = ((const float4*)src)[i];
    f16x4 a, b; half_t t0, t1;
    split_f32(v.x, t0, t1); a[0] = t0; b[0] = t1;
    split_f32(v.y, t0, t1); a[1] = t0; b[1] = t1;
    split_f32(v.z, t0, t1); a[2] = t0; b[2] = t1;
    split_f32(v.w, t0, t1); a[3] = t0; b[3] = t1;
    ((f16x4*)hi)[i] = a;
    ((f16x4*)lo)[i] = b;
}

// ---------------------------------------------------------------------------
// init: h0 = h1 = sem_f (+ splits). inputs/finished now set by gru0 at t=0.
// ---------------------------------------------------------------------------
__global__ __launch_bounds__(256)
void init_kernel(const float* __restrict__ sem_f,
                 float* __restrict__ h0, float* __restrict__ h1,
                 half_t* __restrict__ h0a, half_t* __restrict__ h0b,
                 half_t* __restrict__ h1a, half_t* __restrict__ h1b)
{
    const int i = blockIdx.x * 256 + threadIdx.x;
    if (i < B_ * H_) {
        const float v = sem_f[i];
        h0[i] = v; h1[i] = v;
        half_t a, b; split_f32(v, a, b);
        h0a[i] = a; h0b[i] = b;
        h1a[i] = a; h1b[i] = b;
    }
}

// ---------------------------------------------------------------------------
// gru0: fused finalize-prologue + barrier-free GEMM -> PRE0.
// grid 192: ct = b%48 (ct<24 -> ih part), rt = b/48 (64-row group).
// ih blocks: prologue reduces argmax(t-1) partials for their 64 rows into
//   s_tok (reads only; ct==0 writes decoded/mask + inputs/finished parity p),
//   then GEMM reads A directly from emb[tok] fp32, splitting on the fly.
// hh blocks: A = h0 splits (from gate0 of t-1), unchanged.
// Parity convention: finished[p=t&1] = state after decode(t-1).
// ---------------------------------------------------------------------------
__global__ __launch_bounds__(256, 2)
void gru0_k(const half_t* __restrict__ h0a, const half_t* __restrict__ h0b,
            const half_t* __restrict__ Wia, const half_t* __restrict__ Wib,
            const half_t* __restrict__ Wha, const half_t* __restrict__ Whb,
            const float* __restrict__ b_ih, const float* __restrict__ b_hh,
            float* __restrict__ PRE0,
            const float* __restrict__ emb,
            const float* __restrict__ pmax, const int* __restrict__ pidx,
            int* __restrict__ inputsBuf, int* __restrict__ finishedBuf,
            float* __restrict__ decoded, float* __restrict__ masko, int t)
{
    const int bidx = blockIdx.x;
    const int ct = bidx % 48;
    const int rt = bidx / 48;            // 0..3
    const bool is_ih = (ct < 24);
    const int wrow0 = (is_ih ? ct : ct - 24) * 64;
    const int row0  = rt * 64;
    const float*  bias = is_ih ? b_ih : b_hh;
    const half_t* W0 = is_ih ? Wia : Wha;
    const half_t* W1 = is_ih ? Wib : Whb;

    const int tid  = threadIdx.x;
    const int wv   = tid >> 6;
    const int wr   = wv >> 1, wc = wv & 1;
    const int lane = tid & 63;
    const int ll   = lane & 15, lg = lane >> 4;

    __shared__ int s_tok[64];

    if (is_ih) {
        const int p = t & 1, q = p ^ 1;
        if (t == 0) {
            if (tid < 64) {
                s_tok[tid] = SOS_;
                if (ct == 0) {
                    inputsBuf[row0 + tid] = SOS_;          // parity 0
                    finishedBuf[row0 + tid] = 0;
                }
            }
        } else {
            for (int rr = wv; rr < 64; rr += 4) {          // one wave per row
                const int brow = row0 + rr;
                float v = -INFINITY; int ix = 0x7fffffff;
                for (int s = lane; s < 125; s += 64) {
                    const float v2 = pmax[brow * 128 + s];
                    const int   i2 = pidx[brow * 128 + s];
                    if (v2 > v || (v2 == v && i2 < ix)) { v = v2; ix = i2; }
                }
#pragma unroll
                for (int m = 1; m < 64; m <<= 1) {
                    const float ov = __shfl_xor(v, m);
                    const int   oi = __shfl_xor(ix, m);
                    if (ov > v || (ov == v && oi < ix)) { v = ov; ix = oi; }
                }
                if (lane == 0) {
                    const int finOld = finishedBuf[q * 256 + brow];
                    const int inpOld = inputsBuf[q * 256 + brow];
                    const int dec = ix;
                    const int tok = finOld ? inpOld : dec;
                    s_tok[rr] = tok;
                    if (ct == 0) {
                        decoded[brow * M_ + (t - 1)] = finOld ? -1.0f : (float)dec;
                        masko  [brow * M_ + (t - 1)] = finOld ? 0.0f : 1.0f;
                        inputsBuf[p * 256 + brow] = tok;
                        finishedBuf[p * 256 + brow] = finOld ? 1 : (dec == EOS_ ? 1 : 0);
                    }
                }
            }
        }
        __syncthreads();
    }

    f32x4 accM[2][2] = {};
    f32x4 accC[2][2] = {};
    const size_t boff0 = ((size_t)(wrow0 + 32*wc + ll) << 9) + (lg << 3);

    if (is_ih) {
        // A directly from emb fp32 via token indirection, split on the fly
        const int rA = 32*wr + ll;
        const float* ea = emb + (size_t)s_tok[rA]      * H_ + (lg << 3);
        const float* eb = emb + (size_t)s_tok[rA + 16] * H_ + (lg << 3);
#pragma unroll 2
        for (int k0 = 0; k0 < H_; k0 += 32) {
            const float4 fa0 = *(const float4*)(ea + k0);
            const float4 fa1 = *(const float4*)(ea + k0 + 4);
            const float4 fb0 = *(const float4*)(eb + k0);
            const float4 fb1 = *(const float4*)(eb + k0 + 4);
            f16x8 a0[2], a1[2], b0[2], b1[2];
            {
                const float fa[8] = {fa0.x,fa0.y,fa0.z,fa0.w, fa1.x,fa1.y,fa1.z,fa1.w};
                const float fb[8] = {fb0.x,fb0.y,fb0.z,fb0.w, fb1.x,fb1.y,fb1.z,fb1.w};
#pragma unroll
                for (int e = 0; e < 8; ++e) {
                    half_t hi, lo;
                    split_f32(fa[e], hi, lo); a0[0][e] = hi; a1[0][e] = lo;
                    split_f32(fb[e], hi, lo); a0[1][e] = hi; a1[1][e] = lo;
                }
            }
            b0[0] = *(const f16x8*)(W0 + boff0 + k0);
            b0[1] = *(const f16x8*)(W0 + boff0 + 8192 + k0);
            b1[0] = *(const f16x8*)(W1 + boff0 + k0);
            b1[1] = *(const f16x8*)(W1 + boff0 + 8192 + k0);
#pragma unroll
            for (int cf = 0; cf < 2; ++cf)
#pragma unroll
                for (int rf = 0; rf < 2; ++rf) {
                    accM[rf][cf] = __builtin_amdgcn_mfma_f32_16x16x32_f16(a0[rf], b0[cf], accM[rf][cf], 0,0,0);
                    accC[rf][cf] = __builtin_amdgcn_mfma_f32_16x16x32_f16(a0[rf], b1[cf], accC[rf][cf], 0,0,0);
                    accC[rf][cf] = __builtin_amdgcn_mfma_f32_16x16x32_f16(a1[rf], b0[cf], accC[rf][cf], 0,0,0);
                }
        }
    } else {
        const size_t aoff0 = ((size_t)(row0 + 32*wr + ll) << 9) + (lg << 3);
#pragma unroll 2
        for (int k0 = 0; k0 < H_; k0 += 32) {
            f16x8 a0[2], a1[2], b0[2], b1[2];
            a0[0] = *(const f16x8*)(h0a + aoff0 + k0);
            a0[1] = *(const f16x8*)(h0a + aoff0 + 8192 + k0);
            a1[0] = *(const f16x8*)(h0b + aoff0 + k0);
            a1[1] = *(const f16x8*)(h0b + aoff0 + 8192 + k0);
            b0[0] = *(const f16x8*)(W0 + boff0 + k0);
            b0[1] = *(const f16x8*)(W0 + boff0 + 8192 + k0);
            b1[0] = *(const f16x8*)(W1 + boff0 + k0);
            b1[1] = *(const f16x8*)(W1 + boff0 + 8192 + k0);
#pragma unroll
            for (int cf = 0; cf < 2; ++cf)
#pragma unroll
                for (int rf = 0; rf < 2; ++rf) {
                    accM[rf][cf] = __builtin_amdgcn_mfma_f32_16x16x32_f16(a0[rf], b0[cf], accM[rf][cf], 0,0,0);
                    accC[rf][cf] = __builtin_amdgcn_mfma_f32_16x16x32_f16(a0[rf], b1[cf], accC[rf][cf], 0,0,0);
                    accC[rf][cf] = __builtin_amdgcn_mfma_f32_16x16x32_f16(a1[rf], b0[cf], accC[rf][cf], 0,0,0);
                }
        }
    }

#pragma unroll
    for (int cf = 0; cf < 2; ++cf) {
        const int cl = 32*wc + 16*cf + ll;
        const float bv = bias[wrow0 + cl];
        const int c = ct * 64 + cl;
#pragma unroll
        for (int rf = 0; rf < 2; ++rf)
#pragma unroll
            for (int r = 0; r < 4; ++r) {
                const int row = row0 + 32*wr + 16*rf + lg*4 + r;
                PRE0[(size_t)row * 3072 + c] = accM[rf][cf][r] + accC[rf][cf][r] * INV_SCALE + bv;
            }
    }
}

// ---------------------------------------------------------------------------
// gru1: barrier-free GEMM (round-13 body), A = h0 splits / h1 splits.
// ---------------------------------------------------------------------------
__global__ __launch_bounds__(256, 2)
void gru_bf_k(const half_t* __restrict__ Aia, const half_t* __restrict__ Aib,
              const half_t* __restrict__ Aha, const half_t* __restrict__ Ahb,
              const half_t* __restrict__ Wia, const half_t* __restrict__ Wib,
              const half_t* __restrict__ Wha, const half_t* __restrict__ Whb,
              const float* __restrict__ b_ih, const float* __restrict__ b_hh,
              float* __restrict__ PRE)
{
    const int bidx = blockIdx.x;
    const int ct = bidx % 48;
    const int rt = bidx / 48;
    const bool is_ih = (ct < 24);
    const int wrow0 = (is_ih ? ct : ct - 24) * 64;
    const int row0  = rt * 64;
    const float*  bias = is_ih ? b_ih : b_hh;
    const half_t* Aa = is_ih ? Aia : Aha;
    const half_t* Ab = is_ih ? Aib : Ahb;
    const half_t* W0 = is_ih ? Wia : Wha;
    const half_t* W1 = is_ih ? Wib : Whb;

    const int tid  = threadIdx.x;
    const int wv   = tid >> 6;
    const int wr   = wv >> 1, wc = wv & 1;
    const int lane = tid & 63;
    const int ll   = lane & 15, lg = lane >> 4;

    f32x4 accM[2][2] = {};
    f32x4 accC[2][2] = {};

    const size_t aoff0 = ((size_t)(row0 + 32*wr + ll) << 9) + (lg << 3);
    const size_t boff0 = ((size_t)(wrow0 + 32*wc + ll) << 9) + (lg << 3);

#pragma unroll 2
    for (int k0 = 0; k0 < H_; k0 += 32) {
        f16x8 a0[2], a1[2], b0[2], b1[2];
        a0[0] = *(const f16x8*)(Aa + aoff0 + k0);
        a0[1] = *(const f16x8*)(Aa + aoff0 + 8192 + k0);
        a1[0] = *(const f16x8*)(Ab + aoff0 + k0);
        a1[1] = *(const f16x8*)(Ab + aoff0 + 8192 + k0);
        b0[0] = *(const f16x8*)(W0 + boff0 + k0);
        b0[1] = *(const f16x8*)(W0 + boff0 + 8192 + k0);
        b1[0] = *(const f16x8*)(W1 + boff0 + k0);
        b1[1] = *(const f16x8*)(W1 + boff0 + 8192 + k0);
#pragma unroll
        for (int cf = 0; cf < 2; ++cf)
#pragma unroll
            for (int rf = 0; rf < 2; ++rf) {
                accM[rf][cf] = __builtin_amdgcn_mfma_f32_16x16x32_f16(a0[rf], b0[cf], accM[rf][cf], 0,0,0);
                accC[rf][cf] = __builtin_amdgcn_mfma_f32_16x16x32_f16(a0[rf], b1[cf], accC[rf][cf], 0,0,0);
                accC[rf][cf] = __builtin_amdgcn_mfma_f32_16x16x32_f16(a1[rf], b0[cf], accC[rf][cf], 0,0,0);
            }
    }

#pragma unroll
    for (int cf = 0; cf < 2; ++cf) {
        const int cl = 32*wc + 16*cf + ll;
        const float bv = bias[wrow0 + cl];
        const int c = ct * 64 + cl;
#pragma unroll
        for (int rf = 0; rf < 2; ++rf)
#pragma unroll
            for (int r = 0; r < 4; ++r) {
                const int row = row0 + 32*wr + 16*rf + lg*4 + r;
                PRE[(size_t)row * 3072 + c] = accM[rf][cf][r] + accC[rf][cf][r] * INV_SCALE + bv;
            }
    }
}

// ---------------------------------------------------------------------------
// GRU gate math; in-place h update with freeze + fp16x2 split emit.
// ---------------------------------------------------------------------------
__global__ __launch_bounds__(256)
void gate_kernel(const float* __restrict__ PRE,
                 float* __restrict__ h,
                 half_t* __restrict__ ha, half_t* __restrict__ hb,
                 const int* __restrict__ finishedBuf, int t)
{
    const int idx = blockIdx.x * 256 + threadIdx.x;
    const int b = idx >> 9;
    const int j = idx & 511;
    if (finishedBuf[(t & 1) * 256 + b]) return;
    const float* p = PRE + (size_t)b * 3072;
    const float ir = p[j],        iz = p[512 + j],  in_ = p[1024 + j];
    const float hr = p[1536 + j], hz = p[2048 + j], hn  = p[2560 + j];
    const float r = 1.0f / (1.0f + expf(-(ir + hr)));
    const float z = 1.0f / (1.0f + expf(-(iz + hz)));
    const float n = tanhf(in_ + r * hn);
    const float hv = (1.0f - z) * n + z * h[idx];
    h[idx] = hv;
    half_t a, bb; split_f32(hv, a, bb);
    ha[idx] = a; hb[idx] = bb;
}

// ---------------------------------------------------------------------------
// FC GEMM (round-3 body, proven): 128-col x 64-row tiles, grid (125,4).
// ---------------------------------------------------------------------------
__global__ __launch_bounds__(256)
void fc_gemm_mfma(const half_t* __restrict__ Aa, const half_t* __restrict__ Ab,
                  const half_t* __restrict__ W0, const half_t* __restrict__ W1,
                  const float* __restrict__ fcb,
                  const int* __restrict__ finishedBuf,
                  float* __restrict__ logits,
                  float* __restrict__ pmax, int* __restrict__ pidx, int t)
{
    const int ct = blockIdx.x;            // 0..124
    const int rt = blockIdx.y;            // 0..3
    const int col0 = ct * 128;
    const int row0 = rt * 64;
    const int p = t & 1;

    __shared__ half_t W0s[128][40];
    __shared__ half_t W1s[128][40];
    __shared__ float  pmS[64][2];
    __shared__ int    piS[64][2];

    const int tid  = threadIdx.x;
    const int wv   = tid >> 6;
    const int wr   = wv >> 1, wc = wv & 1;
    const int lane = tid & 63;
    const int ll   = lane & 15, lg = lane >> 4;

    const int sc = tid >> 1;
    const int sk = (tid & 1) * 16;
    const half_t* wp0 = W0 + (size_t)(col0 + sc) * H_ + sk;
    const half_t* wp1 = W1 + (size_t)(col0 + sc) * H_ + sk;

    f32x4 accM[2][4] = {};
    f32x4 accC[2][4] = {};

    for (int k0 = 0; k0 < H_; k0 += 32) {
        const f16x8 s0 = *(const f16x8*)(wp0 + k0);
        const f16x8 s1 = *(const f16x8*)(wp0 + k0 + 8);
        const f16x8 s2 = *(const f16x8*)(wp1 + k0);
        const f16x8 s3 = *(const f16x8*)(wp1 + k0 + 8);
        __syncthreads();
        *(f16x8*)&W0s[sc][sk]     = s0;
        *(f16x8*)&W0s[sc][sk + 8] = s1;
        *(f16x8*)&W1s[sc][sk]     = s2;
        *(f16x8*)&W1s[sc][sk + 8] = s3;
        __syncthreads();

        f16x8 a0[2], a1[2];
#pragma unroll
        for (int rf = 0; rf < 2; ++rf) {
            const size_t off = ((size_t)(row0 + 32*wr + 16*rf + ll) << 9) + k0 + (lg << 3);
            a0[rf] = *(const f16x8*)(Aa + off);
            a1[rf] = *(const f16x8*)(Ab + off);
        }
#pragma unroll
        for (int cf = 0; cf < 4; ++cf) {
            const int c = 64*wc + 16*cf + ll;
            const f16x8 b0 = *(const f16x8*)&W0s[c][lg << 3];
            const f16x8 b1 = *(const f16x8*)&W1s[c][lg << 3];
#pragma unroll
            for (int rf = 0; rf < 2; ++rf) {
                accM[rf][cf] = __builtin_amdgcn_mfma_f32_16x16x32_f16(a0[rf], b0, accM[rf][cf], 0,0,0);
                accC[rf][cf] = __builtin_amdgcn_mfma_f32_16x16x32_f16(a0[rf], b1, accC[rf][cf], 0,0,0);
                accC[rf][cf] = __builtin_amdgcn_mfma_f32_16x16x32_f16(a1[rf], b0, accC[rf][cf], 0,0,0);
            }
        }
    }

    int fin[2][4];
#pragma unroll
    for (int rf = 0; rf < 2; ++rf)
#pragma unroll
        for (int r = 0; r < 4; ++r)
            fin[rf][r] = finishedBuf[p * 256 + row0 + 32*wr + 16*rf + lg*4 + r];

    float bvv[2][4];
    int   bii[2][4];
#pragma unroll
    for (int rf = 0; rf < 2; ++rf)
#pragma unroll
        for (int r = 0; r < 4; ++r) { bvv[rf][r] = -INFINITY; bii[rf][r] = 0x7fffffff; }

#pragma unroll
    for (int cf = 0; cf < 4; ++cf) {
        const int col = col0 + 64*wc + 16*cf + ll;
        const float bv = fcb[col];
#pragma unroll
        for (int rf = 0; rf < 2; ++rf) {
#pragma unroll
            for (int r = 0; r < 4; ++r) {
                const int row = row0 + 32*wr + 16*rf + lg*4 + r;
                const float raw = accM[rf][cf][r] + accC[rf][cf][r] * INV_SCALE + bv;
                logits[((size_t)row * M_ + t) * V_ + col] = fin[rf][r] ? 0.0f : raw;
                if (raw > bvv[rf][r]) { bvv[rf][r] = raw; bii[rf][r] = col; } // cf asc
            }
        }
    }

#pragma unroll
    for (int rf = 0; rf < 2; ++rf) {
#pragma unroll
        for (int r = 0; r < 4; ++r) {
            float v = bvv[rf][r]; int ix = bii[rf][r];
#pragma unroll
            for (int m = 1; m < 16; m <<= 1) {
                const float ov = __shfl_xor(v, m);
                const int   oi = __shfl_xor(ix, m);
                if (ov > v || (ov == v && oi < ix)) { v = ov; ix = oi; }
            }
            if (ll == 0) {
                const int lr = 32*wr + 16*rf + lg*4 + r;
                pmS[lr][wc] = v; piS[lr][wc] = ix;
            }
        }
    }
    __syncthreads();
    if (tid < 64) {
        float v = pmS[tid][0]; int ix = piS[tid][0];
        const float v2 = pmS[tid][1]; const int i2 = piS[tid][1];
        if (v2 > v || (v2 == v && i2 < ix)) { v = v2; ix = i2; }
        pmax[(row0 + tid) * 128 + ct] = v;
        pidx[(row0 + tid) * 128 + ct] = ix;
    }
}

// ---------------------------------------------------------------------------
// final: decoded/mask for step M-1 from the last fc partials.
// ---------------------------------------------------------------------------
__global__ __launch_bounds__(256)
void final_k(const float* __restrict__ pmax, const int* __restrict__ pidx,
             const int* __restrict__ finishedBuf,
             float* __restrict__ decoded, float* __restrict__ masko)
{
    const int row0 = blockIdx.x * 64;
    const int tid = threadIdx.x;
    const int wv = tid >> 6, lane = tid & 63;
    const int q = (M_ - 1) & 1;     // finished[q] = state after decode M-2
    for (int rr = wv; rr < 64; rr += 4) {
        const int brow = row0 + rr;
        float v = -INFINITY; int ix = 0x7fffffff;
        for (int s = lane; s < 125; s += 64) {
            const float v2 = pmax[brow * 128 + s];
            const int   i2 = pidx[brow * 128 + s];
            if (v2 > v || (v2 == v && i2 < ix)) { v = v2; ix = i2; }
        }
#pragma unroll
        for (int m = 1; m < 64; m <<= 1) {
            const float ov = __shfl_xor(v, m);
            const int   oi = __shfl_xor(ix, m);
            if (ov > v || (ov == v && oi < ix)) { v = ov; ix = oi; }
        }
        if (lane == 0) {
            const int finOld = finishedBuf[q * 256 + brow];
            decoded[brow * M_ + (M_ - 1)] = finOld ? -1.0f : (float)ix;
            masko  [brow * M_ + (M_ - 1)] = finOld ? 0.0f : 1.0f;
        }
    }
}

// ---------------------------------------------------------------------------
extern "C" void kernel_launch(void* const* d_in, const int* in_sizes, int n_in,
                              void* d_out, int out_size, void* d_ws, size_t ws_size,
                              hipStream_t stream)
{
    const float* sem_f = (const float*)d_in[0];
    const float* emb   = (const float*)d_in[1];
    const float* W_ih0 = (const float*)d_in[2];
    const float* W_hh0 = (const float*)d_in[3];
    const float* b_ih0 = (const float*)d_in[4];
    const float* b_hh0 = (const float*)d_in[5];
    const float* W_ih1 = (const float*)d_in[6];
    const float* W_hh1 = (const float*)d_in[7];
    const float* b_ih1 = (const float*)d_in[8];
    const float* b_hh1 = (const float*)d_in[9];
    const float* fc_W  = (const float*)d_in[10];
    const float* fc_b  = (const float*)d_in[11];

    float* out = (float*)d_out;
    float* decoded_out = out;
    float* logits_out  = out + (size_t)B_ * M_;
    float* mask_out    = out + (size_t)B_ * M_ + (size_t)B_ * M_ * V_;

    float*  ws  = (float*)d_ws;
    float*  PRE = ws;                                // 786432
    float*  h0  = ws + 786432;                       // 131072
    float*  h1  = ws + 917504;                       // 131072
    half_t* h0a = (half_t*)(ws + 1048576);           // 65536 f each
    half_t* h0b = (half_t*)(ws + 1114112);
    half_t* h1a = (half_t*)(ws + 1179648);
    half_t* h1b = (half_t*)(ws + 1245184);
    float*  pmax = ws + 1310720;                     // 256*128
    int*    pidx = (int*)(ws + 1343488);             // 256*128
    int*    inputsBuf   = (int*)(ws + 1376256);      // 2 x 256
    int*    finishedBuf = (int*)(ws + 1376768);      // 2 x 256
    half_t* wi0a = (half_t*)(ws + 1377280);          // each 393216 f
    half_t* wi0b = (half_t*)(ws + 1770496);
    half_t* wh0a = (half_t*)(ws + 2163712);
    half_t* wh0b = (half_t*)(ws + 2556928);
    half_t* wi1a = (half_t*)(ws + 2950144);
    half_t* wi1b = (half_t*)(ws + 3343360);
    half_t* wh1a = (half_t*)(ws + 3736576);
    half_t* wh1b = (half_t*)(ws + 4129792);
    half_t* fca  = (half_t*)(ws + 4523008);          // 4096000 f each
    half_t* fcbp = (half_t*)(ws + 8619008);
    // total 12,715,008 floats = 50.9 MB

    const int nGru4 = (1536 * 512) / 4;
    const int nFc4  = (V_ * H_) / 4;
    split_weights_k<<<(nGru4 + 255) / 256, 256, 0, stream>>>(W_ih0, wi0a, wi0b, nGru4);
    split_weights_k<<<(nGru4 + 255) / 256, 256, 0, stream>>>(W_hh0, wh0a, wh0b, nGru4);
    split_weights_k<<<(nGru4 + 255) / 256, 256, 0, stream>>>(W_ih1, wi1a, wi1b, nGru4);
    split_weights_k<<<(nGru4 + 255) / 256, 256, 0, stream>>>(W_hh1, wh1a, wh1b, nGru4);
    split_weights_k<<<(nFc4 + 255) / 256, 256, 0, stream>>>(fc_W, fca, fcbp, nFc4);

    init_kernel<<<(B_ * H_ + 255) / 256, 256, 0, stream>>>(
        sem_f, h0, h1, h0a, h0b, h1a, h1b);

    const dim3 fcGrid(125, 4);

    for (int t = 0; t < M_; ++t) {
        gru0_k<<<192, 256, 0, stream>>>(
            h0a, h0b, wi0a, wi0b, wh0a, wh0b, b_ih0, b_hh0, PRE,
            emb, pmax, pidx, inputsBuf, finishedBuf, decoded_out, mask_out, t);
        gate_kernel<<<(B_ * H_) / 256, 256, 0, stream>>>(PRE, h0, h0a, h0b, finishedBuf, t);
        gru_bf_k<<<192, 256, 0, stream>>>(
            h0a, h0b, h1a, h1b, wi1a, wi1b, wh1a, wh1b, b_ih1, b_hh1, PRE);
        gate_kernel<<<(B_ * H_) / 256, 256, 0, stream>>>(PRE, h1, h1a, h1b, finishedBuf, t);
        fc_gemm_mfma<<<fcGrid, 256, 0, stream>>>(
            h1a, h1b, fca, fcbp, fc_b, finishedBuf, logits_out, pmax, pidx, t);
    }
    final_k<<<4, 256, 0, stream>>>(pmax, pidx, finishedBuf, decoded_out, mask_out);
}